// Round 3
// baseline (5565.051 us; speedup 1.0000x reference)
//
#include <hip/hip_runtime.h>
#include <stdint.h>

#define NB    64
#define LSEQ  2048
#define IND   128
#define HID   256
#define ACTD  18
#define G3    768            // 3*HID
#define MROWS (NB*LSEQ)      // 131072

typedef _Float16 half_t;
typedef half_t half2_t __attribute__((ext_vector_type(2)));

// ---------------- dtype helpers (manual bf16) ------------
__device__ __forceinline__ float bf2f(unsigned short u) { return __uint_as_float(((unsigned)u) << 16); }
__device__ __forceinline__ unsigned short f2bf(float f) {
  unsigned u = __float_as_uint(f);
  return (unsigned short)((u + 0x7FFFu + ((u >> 16) & 1u)) >> 16);
}
template<typename T> __device__ __forceinline__ float ldv(const T* p);
template<> __device__ __forceinline__ float ldv<float>(const float* p) { return *p; }
template<> __device__ __forceinline__ float ldv<unsigned short>(const unsigned short* p) { return bf2f(*p); }
template<typename T> __device__ __forceinline__ void stv(T* p, float v);
template<> __device__ __forceinline__ void stv<float>(float* p, float v) { *p = v; }
template<> __device__ __forceinline__ void stv<unsigned short>(unsigned short* p, float v) { *p = f2bf(v); }
template<typename T> __device__ __forceinline__ float4 ld4(const T* p);
template<> __device__ __forceinline__ float4 ld4<float>(const float* p) { return *(const float4*)p; }
template<> __device__ __forceinline__ float4 ld4<unsigned short>(const unsigned short* p) {
  ushort4 u = *(const ushort4*)p;
  float4 r; r.x = bf2f(u.x); r.y = bf2f(u.y); r.z = bf2f(u.z); r.w = bf2f(u.w); return r;
}

__device__ __forceinline__ float fdot2f(half2_t a, half2_t b, float c) {
#if __has_builtin(__builtin_amdgcn_fdot2)
  return __builtin_amdgcn_fdot2(a, b, c, false);
#else
  return fmaf((float)a.x, (float)b.x, fmaf((float)a.y, (float)b.y, c));
#endif
}

__device__ __forceinline__ float sigmoid_f(float x) { return 1.f / (1.f + __expf(-x)); }
__device__ __forceinline__ float tanh_f(float x) {
  const float t = __expf(-2.f * fabsf(x));
  const float r = (1.f - t) / (1.f + t);
  return x < 0.f ? -r : r;
}

// skewed LDS index for h: half2-pair k2 -> k2 + (k2>>4)*4  (banks conflict-free)
__device__ __forceinline__ int skew2(int k2) { return k2 + ((k2 >> 4) << 2); }

// ---------------- generic fp32-accumulate GEMM: C[M,N] = op(A[M,K]) * W[N,K]^T + b --
template<typename IT, typename OT, bool RELU_IN, bool RELU_OUT, int K>
__global__ __launch_bounds__(256) void rnnq_gemm(const IT* __restrict__ A, const float* __restrict__ W,
                                                 const float* __restrict__ bias, OT* __restrict__ C,
                                                 int N) {
  __shared__ float At[32][68];
  __shared__ float Wt[32][136];
  const int t  = threadIdx.x;
  const long m0 = (long)blockIdx.x * 64;
  const int n0 = blockIdx.y * 128;
  const int ty = t >> 4, tx = t & 15;
  const int sr = t >> 2, skq = (t & 3) * 4;
  const int wc = t >> 1, wkh = (t & 1) * 16;
  float acc[4][8] = {{0.f}};
  for (int kc = 0; kc < K; kc += 32) {
    float4 a0 = ld4(A + (m0 + sr) * (size_t)K + kc + skq);
    float4 a1 = ld4(A + (m0 + sr) * (size_t)K + kc + skq + 16);
    if (RELU_IN) {
      a0.x = fmaxf(a0.x, 0.f); a0.y = fmaxf(a0.y, 0.f); a0.z = fmaxf(a0.z, 0.f); a0.w = fmaxf(a0.w, 0.f);
      a1.x = fmaxf(a1.x, 0.f); a1.y = fmaxf(a1.y, 0.f); a1.z = fmaxf(a1.z, 0.f); a1.w = fmaxf(a1.w, 0.f);
    }
    const float* wp = W + (size_t)(n0 + wc) * K + kc + wkh;
    float4 w0 = *(const float4*)(wp + 0);
    float4 w1 = *(const float4*)(wp + 4);
    float4 w2 = *(const float4*)(wp + 8);
    float4 w3 = *(const float4*)(wp + 12);
    At[skq+0][sr] = a0.x; At[skq+1][sr] = a0.y; At[skq+2][sr] = a0.z; At[skq+3][sr] = a0.w;
    At[skq+16][sr] = a1.x; At[skq+17][sr] = a1.y; At[skq+18][sr] = a1.z; At[skq+19][sr] = a1.w;
    Wt[wkh+0][wc] = w0.x; Wt[wkh+1][wc] = w0.y; Wt[wkh+2][wc] = w0.z; Wt[wkh+3][wc] = w0.w;
    Wt[wkh+4][wc] = w1.x; Wt[wkh+5][wc] = w1.y; Wt[wkh+6][wc] = w1.z; Wt[wkh+7][wc] = w1.w;
    Wt[wkh+8][wc] = w2.x; Wt[wkh+9][wc] = w2.y; Wt[wkh+10][wc] = w2.z; Wt[wkh+11][wc] = w2.w;
    Wt[wkh+12][wc] = w3.x; Wt[wkh+13][wc] = w3.y; Wt[wkh+14][wc] = w3.z; Wt[wkh+15][wc] = w3.w;
    __syncthreads();
    #pragma unroll
    for (int k = 0; k < 32; ++k) {
      const float4 av  = *(const float4*)&At[k][ty*4];
      const float4 bv0 = *(const float4*)&Wt[k][tx*8];
      const float4 bv1 = *(const float4*)&Wt[k][tx*8+4];
      const float am[4] = {av.x, av.y, av.z, av.w};
      const float bm[8] = {bv0.x, bv0.y, bv0.z, bv0.w, bv1.x, bv1.y, bv1.z, bv1.w};
      #pragma unroll
      for (int i = 0; i < 4; ++i)
        #pragma unroll
        for (int jj = 0; jj < 8; ++jj)
          acc[i][jj] = fmaf(am[i], bm[jj], acc[i][jj]);
    }
    __syncthreads();
  }
  #pragma unroll
  for (int i = 0; i < 4; ++i) {
    const long r = m0 + ty*4 + i;
    OT* cp = C + r * (size_t)N + n0 + tx*8;
    #pragma unroll
    for (int jj = 0; jj < 8; ++jj) {
      float v = acc[i][jj] + bias[n0 + tx*8 + jj];
      if (RELU_OUT) v = fmaxf(v, 0.f);
      stv(cp + jj, v);
    }
  }
}

// ---------------- fc2: Q[131072,18] = X[131072,256] * W2[18,256]^T + b2 -------------
template<typename YT>
__global__ __launch_bounds__(256) void rnnq_fc2(const YT* __restrict__ X, const float* __restrict__ W2,
                                                const float* __restrict__ b2, float* __restrict__ Q) {
  __shared__ float xs[32][260];
  __shared__ float ws2[ACTD][260];
  const int t = threadIdx.x;
  const long r0 = (long)blockIdx.x * 32;
  for (int i = t; i < 32*64; i += 256) {
    const int r = i >> 6, c4 = (i & 63) * 4;
    const float4 v = ld4(X + (r0 + r) * (size_t)HID + c4);
    *(float4*)&xs[r][c4] = v;
  }
  for (int i = t; i < ACTD*64; i += 256) {
    const int a = i >> 6, c4 = (i & 63) * 4;
    *(float4*)&ws2[a][c4] = *(const float4*)(W2 + a*HID + c4);
  }
  __syncthreads();
  for (int idx = t; idx < 32*ACTD; idx += 256) {
    const int r = idx / ACTD, a = idx - r*ACTD;
    float s0 = 0.f, s1 = 0.f;
    #pragma unroll
    for (int k4 = 0; k4 < HID/4; k4 += 2) {
      const float4 xv = *(const float4*)&xs[r][k4*4];
      const float4 wv = *(const float4*)&ws2[a][k4*4];
      s0 = fmaf(xv.x, wv.x, s0); s0 = fmaf(xv.y, wv.y, s0);
      s0 = fmaf(xv.z, wv.z, s0); s0 = fmaf(xv.w, wv.w, s0);
      const float4 xv2 = *(const float4*)&xs[r][k4*4+4];
      const float4 wv2 = *(const float4*)&ws2[a][k4*4+4];
      s1 = fmaf(xv2.x, wv2.x, s1); s1 = fmaf(xv2.y, wv2.y, s1);
      s1 = fmaf(xv2.z, wv2.z, s1); s1 = fmaf(xv2.w, wv2.w, s1);
    }
    Q[(r0 + r) * ACTD + a] = s0 + s1 + b2[a];
  }
}

// ---------------- scan: one block per row, 1024 threads ----------------------------
// thread = (jg = t>>3 owns j = jg*2 + {0,1}, kq = t&7 owns k = kq*32..+31).
// Weights: 96 half2/thread in VGPRs (fits 128-cap, no AGPR churn).
// h in LDS as f16 with skewed layout (bank-conflict-free). One barrier/step.
// Epilogue distributed: lane kq handles j = jg*2+kq for kq<2 (full sums present
// in all kq lanes after the 3-stage butterfly).
template<typename GIT>
__global__ __launch_bounds__(1024, 4) void rnnq_scan2(
    const GIT* __restrict__ gi, const int* __restrict__ dones,
    const float* __restrict__ w_hh, const float* __restrict__ b_hh, const float* __restrict__ b_ih,
    const float* __restrict__ h0, float* __restrict__ gru_out, float* __restrict__ next_hx) {
  const int row = blockIdx.x;       // 0..127
  const int n = row & 63;
  const bool is_main = row < 64;
  const int t = threadIdx.x;
  const int jg = t >> 3;            // 0..127
  const int kq = t & 7;             // 0..7
  const int j0 = jg * 2;

  __shared__ half2_t hb[2][160];    // skewed: pair k2 at index skew2(k2)
  __shared__ float sbih[G3];
  __shared__ float sbhh[G3];
  __shared__ int cred[16];

  // ---- c = last done index for this n ----
  int cmax = 0;
  for (int i = t; i < LSEQ; i += 1024) if (dones[n*LSEQ + i]) cmax = i;  // ascending -> keeps max
  #pragma unroll
  for (int m = 1; m < 64; m <<= 1) { int o = __shfl_xor(cmax, m, 64); cmax = cmax > o ? cmax : o; }
  if ((t & 63) == 0) cred[t >> 6] = cmax;
  for (int i = t; i < G3; i += 1024) { sbih[i] = b_ih[i]; sbhh[i] = b_hh[i]; }
  __syncthreads();
  int c = cred[0];
  #pragma unroll
  for (int w = 1; w < 16; ++w) c = c > cred[w] ? c : cred[w];
  const int off = is_main ? 0 : c;

  // ---- pack this thread's w_hh slice: [3 gates][2 j][32 k] = 96 half2 ----
  half2_t wpk[3][2][16];
  #pragma unroll
  for (int g = 0; g < 3; ++g)
    #pragma unroll
    for (int jj = 0; jj < 2; ++jj) {
      const float* wp = w_hh + ((size_t)(g*HID + j0 + jj))*HID + kq*32;
      #pragma unroll
      for (int q2 = 0; q2 < 8; ++q2) {
        const float4 v = *(const float4*)(wp + q2*4);
        half2_t a; a.x = (half_t)v.x; a.y = (half_t)v.y;
        half2_t b; b.x = (half_t)v.z; b.y = (half_t)v.w;
        wpk[g][jj][q2*2]   = a;
        wpk[g][jj][q2*2+1] = b;
      }
    }

  // ---- epilogue lane state: lane kq<2 owns j = j0+kq ----
  const bool ep = (kq < 2);
  const int j = j0 + kq;            // valid when ep
  const int hidx = skew2(j >> 1) * 2 + (j & 1);   // half-granular skewed index
  float hprev = 0.f, gr = 0.f, gz = 0.f, gn = 0.f;
  int dcur = 0;
  if (ep) {
    hprev = h0[n*HID + j];
    ((half_t*)&hb[0][0])[hidx] = (half_t)hprev;
    dcur = dones[n*LSEQ + off];
    const GIT* gp = gi + ((size_t)n*LSEQ + off) * G3;
    gr = ldv(gp + j); gz = ldv(gp + HID + j); gn = ldv(gp + 2*HID + j);
  }
  __syncthreads();

  #pragma unroll 1
  for (int step = 0; step < LSEQ; ++step) {
    const int cur = step & 1, nxt = cur ^ 1;
    // ---- matvec partials: 6 accumulators, 96 dot2 ----
    float aR0=0.f, aR1=0.f, aZ0=0.f, aZ1=0.f, aN0=0.f, aN1=0.f;
    const half2_t* hbase = &hb[cur][kq * 20];
    #pragma unroll
    for (int q4 = 0; q4 < 4; ++q4) {
      half2_t hv[4];
      *(float4*)hv = *(const float4*)&hbase[q4*4];
      #pragma unroll
      for (int u = 0; u < 4; ++u) {
        const int w = q4*4 + u;
        aR0 = fdot2f(wpk[0][0][w], hv[u], aR0);
        aR1 = fdot2f(wpk[0][1][w], hv[u], aR1);
        aZ0 = fdot2f(wpk[1][0][w], hv[u], aZ0);
        aZ1 = fdot2f(wpk[1][1][w], hv[u], aZ1);
        aN0 = fdot2f(wpk[2][0][w], hv[u], aN0);
        aN1 = fdot2f(wpk[2][1][w], hv[u], aN1);
      }
    }
    // ---- butterfly reduce over kq (lane bits 0..2): 18 shfl ----
    aR0 += __shfl_xor(aR0, 1, 64); aR0 += __shfl_xor(aR0, 2, 64); aR0 += __shfl_xor(aR0, 4, 64);
    aR1 += __shfl_xor(aR1, 1, 64); aR1 += __shfl_xor(aR1, 2, 64); aR1 += __shfl_xor(aR1, 4, 64);
    aZ0 += __shfl_xor(aZ0, 1, 64); aZ0 += __shfl_xor(aZ0, 2, 64); aZ0 += __shfl_xor(aZ0, 4, 64);
    aZ1 += __shfl_xor(aZ1, 1, 64); aZ1 += __shfl_xor(aZ1, 2, 64); aZ1 += __shfl_xor(aZ1, 4, 64);
    aN0 += __shfl_xor(aN0, 1, 64); aN0 += __shfl_xor(aN0, 2, 64); aN0 += __shfl_xor(aN0, 4, 64);
    aN1 += __shfl_xor(aN1, 1, 64); aN1 += __shfl_xor(aN1, 2, 64); aN1 += __shfl_xor(aN1, 4, 64);

    if (ep) {
      const float sR = kq ? aR1 : aR0;
      const float sZ = kq ? aZ1 : aZ0;
      const float sN = kq ? aN1 : aN0;
      const float m = dcur ? 0.f : 1.f;
      const float hold = m * hprev;
      const float rr = sigmoid_f(gr + m * sR + sbhh[j]);
      const float zz = sigmoid_f(gz + m * sZ + sbhh[HID + j]);
      const float nn = tanh_f(gn + rr * (m * sN + sbhh[2*HID + j]));
      const float hnew = (1.f - zz) * nn + zz * hold;
      hprev = hnew;
      ((half_t*)&hb[nxt][0])[hidx] = (half_t)hnew;
      if (is_main) {
        gru_out[((size_t)n*LSEQ + step)*HID + j] = hnew;
      } else if (step == LSEQ - 1) {
        next_hx[n*HID + j] = hnew;
      }
      if (step + 1 < LSEQ) {
        const int idx = off + step + 1;
        if (idx < LSEQ) {
          dcur = dones[n*LSEQ + idx];
          const GIT* gp = gi + ((size_t)n*LSEQ + idx) * G3;
          gr = ldv(gp + j); gz = ldv(gp + HID + j); gn = ldv(gp + 2*HID + j);
        } else {
          dcur = 0;
          gr = sbih[j]; gz = sbih[HID + j]; gn = sbih[2*HID + j];
        }
      }
    }
    __syncthreads();
  }
}

// ---------------- host-side pipeline ----------------
template<typename GIT, typename YT>
static void run_pipeline(const float* state, const float* h0, const int* dones,
                         const float* w_ih, const float* w_hh, const float* b_ih, const float* b_hh,
                         const float* fc0_w, const float* fc0_b, const float* fc1_w, const float* fc1_b,
                         const float* fc2_w, const float* fc2_b,
                         float* q_out, float* gru_out, float* hx_out,
                         char* ws, size_t y1_off, hipStream_t stream) {
  GIT* gi = (GIT*)ws;
  YT* y0 = (YT*)ws;                       // aliases gi (gi dead after scan)
  YT* y1 = (YT*)(ws + y1_off);

  rnnq_gemm<float, GIT, false, false, IND><<<dim3(MROWS/64, G3/128), 256, 0, stream>>>(
      state, w_ih, b_ih, gi, G3);
  rnnq_scan2<GIT><<<128, 1024, 0, stream>>>(gi, dones, w_hh, b_hh, b_ih, h0, gru_out, hx_out);
  rnnq_gemm<float, YT, true, true, HID><<<dim3(MROWS/64, HID/128), 256, 0, stream>>>(
      gru_out, fc0_w, fc0_b, y0, HID);
  rnnq_gemm<YT, YT, false, true, HID><<<dim3(MROWS/64, HID/128), 256, 0, stream>>>(
      y0, fc1_w, fc1_b, y1, HID);
  rnnq_fc2<YT><<<MROWS/32, 256, 0, stream>>>(y1, fc2_w, fc2_b, q_out);
}

extern "C" void kernel_launch(void* const* d_in, const int* in_sizes, int n_in,
                              void* d_out, int out_size, void* d_ws, size_t ws_size,
                              hipStream_t stream) {
  const float* state = (const float*)d_in[0];
  const float* h0    = (const float*)d_in[1];
  const int*   dones = (const int*)d_in[2];
  const float* w_ih  = (const float*)d_in[3];
  const float* w_hh  = (const float*)d_in[4];
  const float* b_ih  = (const float*)d_in[5];
  const float* b_hh  = (const float*)d_in[6];
  const float* fc0_w = (const float*)d_in[7];
  const float* fc0_b = (const float*)d_in[8];
  const float* fc1_w = (const float*)d_in[9];
  const float* fc1_b = (const float*)d_in[10];
  const float* fc2_w = (const float*)d_in[11];
  const float* fc2_b = (const float*)d_in[12];

  float* q_out   = (float*)d_out;                       // [64,2048,18]
  float* gru_out = q_out + (size_t)MROWS * ACTD;        // [64,2048,256]
  float* hx_out  = gru_out + (size_t)MROWS * HID;       // [1,64,256]
  char* ws = (char*)d_ws;

  const size_t GI_F32  = (size_t)MROWS * G3 * 4;        // 402,653,184
  const size_t Y_F32   = (size_t)MROWS * HID * 4;       // 134,217,728
  const size_t Y_BF16  = (size_t)MROWS * HID * 2;       //  67,108,864

  if (ws_size >= GI_F32) {
    run_pipeline<float, float>(state, h0, dones, w_ih, w_hh, b_ih, b_hh,
                               fc0_w, fc0_b, fc1_w, fc1_b, fc2_w, fc2_b,
                               q_out, gru_out, hx_out, ws, Y_F32, stream);
  } else if (ws_size >= 2 * Y_F32) {
    run_pipeline<unsigned short, float>(state, h0, dones, w_ih, w_hh, b_ih, b_hh,
                                        fc0_w, fc0_b, fc1_w, fc1_b, fc2_w, fc2_b,
                                        q_out, gru_out, hx_out, ws, Y_F32, stream);
  } else {
    run_pipeline<unsigned short, unsigned short>(state, h0, dones, w_ih, w_hh, b_ih, b_hh,
                                                 fc0_w, fc0_b, fc1_w, fc1_b, fc2_w, fc2_b,
                                                 q_out, gru_out, hx_out, ws, Y_BF16, stream);
  }
}